// Round 22
// baseline (18.519 us; speedup 1.0000x reference)
//
#include <hip/hip_runtime.h>

#define NN 4
#define CC 128
#define HH 64
#define WW 64
#define KK 5
#define K2 25
#define HUP 128
#define WUP 128

typedef int   v4i __attribute__((ext_vector_type(4)));
typedef float v2f __attribute__((ext_vector_type(2)));
typedef float v4f __attribute__((ext_vector_type(4)));

__device__ void llvm_amdgcn_raw_buffer_store_v4f32(v4f data, v4i srsrc,
                                                   int voffset, int soffset,
                                                   int aux)
    __asm("llvm.amdgcn.raw.buffer.store.v4f32");

__device__ inline v4i make_srd(const void* p, unsigned bytes) {
  union { const void* p; unsigned u[2]; } a;
  a.p = p;
  v4i r;
  r.x = (int)a.u[0];
  r.y = (int)(a.u[1] & 0xffffu);  // base[47:32], stride=0
  r.z = (int)bytes;               // num_records in bytes
  r.w = 0x00020000;               // raw dword access
  return r;
}

// DPP wave shifts (R13-proven):
//   wave_shr:1 (0x138): lane w reads w-1 (chain zeros lanes 0,1 = vj-masked).
//   wave_shl:1 (0x130): lane w reads w+1 (chain zeros lanes 62,63).
__device__ inline float dpp_prev1(float x) {  // lane w <- w-1
  return __int_as_float(__builtin_amdgcn_update_dpp(
      0, __float_as_int(x), 0x138, 0xf, 0xf, true));
}
__device__ inline float dpp_next1(float x) {  // lane w <- w+1
  return __int_as_float(__builtin_amdgcn_update_dpp(
      0, __float_as_int(x), 0x130, 0xf, 0xf, true));
}
// quad_perm [1,0,3,2] (0xB1): swap adjacent lane pairs (2j <-> 2j+1).
__device__ inline float dpp_pairswap(float x) {
  return __int_as_float(__builtin_amdgcn_update_dpp(
      0, __float_as_int(x), 0xB1, 0xf, 0xf, false));
}

// grid: NN*HH*4 = 1024 blocks, 256 threads, 66.5 KB LDS -> 2 blocks/CU.
// XCD chunk swizzle (R15-proven). block: cq=bid&3, h=(bid>>2)&63, n=bid>>8.
// thread: w = t&63 (output cols 2w,2w+1), wv = t>>6; c = cq*32 + ci*4 + wv.
//
// R22 = R21 with dwordx4 stores: lane-pair DPP swap packs each channel's
// 2x2 output tile into per-lane 16B rows (even lane: row 2h cols 4j..4j+3,
// odd lane: row 2h+1 same cols) -> 8 store insts/thread instead of 16,
// 1 KB contiguous per wave store.
__global__ __launch_bounds__(256) void carafe_kernel(
    const float* __restrict__ feat, const float* __restrict__ masks,
    float* __restrict__ out) {
  __shared__ float sm[10240];   // features: 32 ch x 5 rows x 64 = 40 KB
  __shared__ float smm[6400];   // masks: 25 k x 2 rows x 128 wup = 25.6 KB

  const int orig = blockIdx.x;
  const int bid = (orig & 7) * 128 + (orig >> 3);  // XCD chunk swizzle
  const int cq = bid & 3;
  const int h  = (bid >> 2) & (HH - 1);
  const int n  = bid >> 8;
  const int t  = threadIdx.x;
  const int w  = t & (WW - 1);
  const int wv = t >> 6;  // wave id = cg

  // --- stage features: slot i = row clamp(h-2+i, 0, 63) of each channel ---
  if (h >= 2 && h <= HH - 3) {
    const int y0 = h - 2;
#pragma unroll
    for (int s = 0; s < 8; ++s) {
      const int cl = wv * 8 + s;
      const float* chg =
          feat + ((size_t)(n * CC + cq * 32 + cl) * HH + y0) * WW;
      __builtin_amdgcn_global_load_lds(
          (const __attribute__((address_space(1))) void*)(chg + w * 4),
          (__attribute__((address_space(3))) void*)(sm + cl * 320), 16, 0, 0);
      __builtin_amdgcn_global_load_lds(
          (const __attribute__((address_space(1))) void*)(chg + 256 + w),
          (__attribute__((address_space(3))) void*)(sm + cl * 320 + 256), 4, 0, 0);
    }
  } else {
    // edge: per-row clamped staging; invalid taps vi-masked.
#pragma unroll
    for (int s = 0; s < 8; ++s) {
      const int cl = wv * 8 + s;
      const float* chb = feat + (size_t)(n * CC + cq * 32 + cl) * (HH * WW);
#pragma unroll
      for (int i = 0; i < KK; ++i) {
        const int r = min(max(h - 2 + i, 0), HH - 1);
        __builtin_amdgcn_global_load_lds(
            (const __attribute__((address_space(1))) void*)(chb + r * WW + w),
            (__attribute__((address_space(3))) void*)(sm + cl * 320 + i * 64),
            4, 0, 0);
      }
    }
  }

  // --- stage masks: per k one 1KB slab masks[n,k,2h:2h+2,:] -> smm[k] ---
#pragma unroll
  for (int j = 0; j < 7; ++j) {
    const int k = wv + 4 * j;
    if (k < K2) {
      const float* mg = masks + (((size_t)n * K2 + k) * HUP + 2 * h) * WUP;
      __builtin_amdgcn_global_load_lds(
          (const __attribute__((address_space(1))) void*)(mg + w * 4),
          (__attribute__((address_space(3))) void*)(smm + k * 256), 16, 0, 0);
    }
  }

  // --- validity (VALU, overlaps staging latency) ---
  float vi[KK], vj[KK];
#pragma unroll
  for (int i = 0; i < KK; ++i) {
    const int r = h - 2 + i;
    vi[i] = (r >= 0 && r < HH) ? 1.f : 0.f;
    const int x = w - 2 + i;
    vj[i] = (x >= 0 && x < WW) ? 1.f : 0.f;
  }

  const v4i srdO = make_srd(out, (unsigned)(NN * CC * HUP * WUP) * 4u);
  const int odd = w & 1;
  // dwordx4 store base: even lane 2j -> row 2h cols 4j (its own vob);
  // odd lane 2j+1 -> row 2h+1 cols 4j (drop +8 col offset, add +512 row).
  int vob = (((n * CC + cq * 32 + wv) * HUP + 2 * h) * WUP + 2 * w) * 4
            + (odd ? 504 : 0);

  __syncthreads();  // all staging complete

  // --- mreg from LDS: smm[k*256 + a*128 + 2w..2w+1] * vv ---
  v2f mreg[K2][2];
#pragma unroll
  for (int k = 0; k < K2; ++k) {
    const int i = k / KK, j = k % KK;
    const float vv = vi[i] * vj[j];
    const v2f u0 = *reinterpret_cast<const v2f*>(&smm[k * 256 + 2 * w]);
    const v2f u1 = *reinterpret_cast<const v2f*>(&smm[k * 256 + 128 + 2 * w]);
    mreg[k][0] = u0 * vv;
    mreg[k][1] = u1 * vv;
  }

  // Even/odd accumulator split (R21-proven).
#define FA(k, e)                                                         \
  do {                                                                   \
    v2f ff; ff.x = (e); ff.y = (e);                                      \
    acc0a += ff * mreg[k][0]; acc1a += ff * mreg[k][1];                  \
  } while (0)
#define FB(k, e)                                                         \
  do {                                                                   \
    v2f ff; ff.x = (e); ff.y = (e);                                      \
    acc0b += ff * mreg[k][0]; acc1b += ff * mreg[k][1];                  \
  } while (0)

  // --- compute: 8 channels/thread; taps r -> m1/p1 -> m2/p2; unroll 4 ---
  int cbase = wv * 320 + w;  // dword base of this thread's channel slot
#pragma unroll 4
  for (int ci = 0; ci < 8; ++ci) {
    v2f acc0a = {0.f, 0.f}, acc1a = {0.f, 0.f};
    v2f acc0b = {0.f, 0.f}, acc1b = {0.f, 0.f};
#pragma unroll
    for (int i = 0; i < KK; ++i) {
      const float r  = sm[cbase + i * 64];  // lane w -> element w of slot i
      const float m1 = dpp_prev1(r);        // x = w-1
      const float p1 = dpp_next1(r);        // x = w+1
      const float m2 = dpp_prev1(m1);       // x = w-2
      const float p2 = dpp_next1(p1);       // x = w+2
      FA(i * KK + 2, r);
      FB(i * KK + 1, m1);
      FA(i * KK + 3, p1);
      FB(i * KK + 0, m2);
      FA(i * KK + 4, p2);
    }
    const v2f acc0 = acc0a + acc0b;  // cols 2w,2w+1 of row 2h
    const v2f acc1 = acc1a + acc1b;  // cols 2w,2w+1 of row 2h+1
    // pair-swap: e0 = partner's acc0, e1 = partner's acc1
    const float e0x = dpp_pairswap(acc0.x), e0y = dpp_pairswap(acc0.y);
    const float e1x = dpp_pairswap(acc1.x), e1y = dpp_pairswap(acc1.y);
    v4f sv;
    sv.x = odd ? e1x : acc0.x;   // even: {acc0, partner acc0} (row 2h)
    sv.y = odd ? e1y : acc0.y;   // odd:  {partner acc1, acc1} (row 2h+1)
    sv.z = odd ? acc1.x : e0x;
    sv.w = odd ? acc1.y : e0y;
    llvm_amdgcn_raw_buffer_store_v4f32(sv, srdO, vob, 0, 0);

    cbase += 4 * 320;            // +4 channels (cg-interleaved)
    vob += 4 * HUP * WUP * 4;
  }
#undef FA
#undef FB
}

extern "C" void kernel_launch(void* const* d_in, const int* in_sizes, int n_in,
                              void* d_out, int out_size, void* d_ws, size_t ws_size,
                              hipStream_t stream) {
  const float* feat  = (const float*)d_in[0];
  const float* masks = (const float*)d_in[1];
  float* out = (float*)d_out;
  (void)in_sizes; (void)n_in; (void)out_size; (void)d_ws; (void)ws_size;
  carafe_kernel<<<NN * HH * 4, 256, 0, stream>>>(feat, masks, out);
}